// Round 5
// baseline (153.072 us; speedup 1.0000x reference)
//
#include <hip/hip_runtime.h>
#include <math.h>

#define NB 65536
#define IMGD 32
#define NPIX 1024
#define PSTRIDE 20

typedef float v2f __attribute__((ext_vector_type(2)));

// Constant tables (same for every image) and per-image derived params.
__device__ float g_r[NPIX];
__device__ float g_th[NPIX];      // theta * 5/(2*pi)  (pre-folded for layer 11)
__device__ float g_par[(size_t)NB * PSTRIDE];

__global__ void init_params_kernel(const float* __restrict__ W) {
    int b = blockIdx.x * blockDim.x + threadIdx.x;

    // block 0 additionally fills the constant pixel tables (4 px/thread)
    if (blockIdx.x == 0) {
        int t = threadIdx.x;
        for (int k = 0; k < 4; ++k) {
            int p = t * 4 + k;
            int x = p >> 5, y = p & 31;
            float dx = (float)(x - 16), dy = (float)(y - 16);
            // exact integer squares; sqrtf correctly rounded -> bitwise match
            g_r[p] = sqrtf(dx * dx + dy * dy);
            // theta = atan2(yy-CY, xx-CX); fold 5/(2*pi) for revolution sin
            g_th[p] = atan2f(dy, dx) * 0.79577471545947668f;
        }
    }
    if (b >= NB) return;
    const float* w = W + (size_t)b * 16;
    float* P = g_par + (size_t)b * PSTRIDE;

    float w0 = w[0], w1 = w[1], w2 = w[2], w3 = w[3], w4 = w[4], w5 = w[5],
          w6 = w[6], w7 = w[7], w8 = w[8], w9 = w[9], w10 = w[10], w11 = w[11],
          w12 = w[12], w13 = w[13], w14 = w[14], w15 = w[15];

    P[0] = w0 * 5.0f;                                   // layer 0 amplitude
    // layer 1: half = floor(clip(|w1|*8, 2, 12)); |w1|*8 exact (pow2 mul)
    float half = floorf(fminf(fmaxf(fabsf(w1) * 8.0f, 2.0f), 12.0f));
    P[1] = 16.0f - half;                                // lo (exact)
    P[2] = 16.0f + half;                                // hi (exact)
    P[3] = w2 * 0.15625f;                               // layer2: rev per x  (10/64)
    P[4] = w3 * 0.15625f;                               // layer3: rev per y
    P[5] = w4 * 0.0390625f;                             // layer4: rev per (x+y) (5/128)
    P[6] = w5 * 0.15625f;                               // layer5: rev offset (10/64)
    P[7] = w6;                                          // bias
    // layer 7 blob center: trunc(16 + w7*5), mul/add un-fused to match ref
    float t7 = __fadd_rn(16.0f, __fmul_rn(w7, 5.0f));
    P[8] = truncf(t7);                                  // bx == by
    float sg = 4.0f + fabsf(w7) * 4.0f;
    P[9] = -1.0f / (2.0f * sg * sg);                    // natural-exp coefficient
    P[10] = w8 * 10.0f;                                 // ring radius (single mul)
    // layer 9: cb = floor(clip(|w9|*8 + 2, 2, 16)); |w9|*8 exact, +2 un-fused
    float cb = floorf(fminf(fmaxf(__fadd_rn(fabsf(w9) * 8.0f, 2.0f), 2.0f), 16.0f));
    P[11] = cb;
    P[12] = 1.0f / cb;
    // layer 10: angle = w10 * f32(pi) rounded once; cos/sin of that exact f32
    // computed in DOUBLE then rounded -> correctly-rounded f32, matches numpy
    // (OCML 1-2ulp f32 trig flipped the |rot|<3 mask -> round-1's 0.10 absmax).
    float ang = __fmul_rn(w10, 3.14159265358979323846f);
    P[13] = (float)cos((double)ang);
    P[14] = (float)sin((double)ang);
    P[15] = w11;                                        // angular sinusoid scale
    P[16] = w12 * 0.1f;                                 // noise_randn coeff
    P[17] = w13 * 0.05f;                                // noise_rand coeff
    P[18] = 1.0f + w14;                                 // contrast
    P[19] = w15;                                        // inversion flag
}

// sin(2*pi*rev): v_fract_f32 + v_sin_f32 (hw sin takes revolutions)
__device__ __forceinline__ float hsin(float rev) {
    return __builtin_amdgcn_sinf(__builtin_amdgcn_fractf(rev));
}

// Exact floor(x/cb) for integer-valued x in [0,32), cb in [2,16].
__device__ __forceinline__ float fdivq(float xf, float cb, float rcb) {
    float q = floorf(xf * rcb);
    q += ((q + 1.0f) * cb <= xf) ? 1.0f : 0.0f;
    q -= ((q * cb) > xf) ? 1.0f : 0.0f;
    return q;
}

// One block = one image. Thread t: y = t&31 fixed, x = (t>>5) + 8j, j=0..3.
// j-pairs processed as float2 ext-vectors -> v_pk_*_f32 (2 f32/lane/issue).
// Discrete layers (square, ring, checker, line, trunc) stay scalar bit-exact;
// packed ops are IEEE-RN per component so shared chains stay exact too.
__global__ __launch_bounds__(256) void decode_kernel(
        const float* __restrict__ nrand,   // noise_randn
        const float* __restrict__ nunif,   // noise_rand
        float* __restrict__ out) {
    int b = blockIdx.x;
    int t = threadIdx.x;
    const float* P = g_par + (size_t)b * PSTRIDE;

    float a0  = P[0],  lo  = P[1],  hi  = P[2],  s2  = P[3],  s3 = P[4];
    float s4  = P[5],  s5o = P[6],  w6  = P[7],  bxy = P[8],  nk = P[9];
    float t8  = P[10], cb  = P[11], rcb = P[12], ca  = P[13], sa = P[14];
    float w11 = P[15], k12 = P[16], k13 = P[17], con = P[18], w15 = P[19];

    __shared__ float4 xt4[32];   // {0.5*sin2 + 0.3*px, xmask(0/1), -0.6*px, gx}
    __shared__ float  xr[32];    // ca*(x-16), un-fused (rot-line x term)
    __shared__ float4 yt4[36];   // padded y+(y>>3): {ysum, ymask(0/0.5), py, gy}
    __shared__ float  stab[63];  // 0.5*sin4(x+y)

    if (t < 32) {
        float xf = (float)t;
        float qx = fdivq(xf, cb, rcb);
        float px = qx - 2.0f * floorf(qx * 0.5f);       // parity 0/1, exact
        float d  = xf - bxy;
        float4 e;
        e.x = 0.5f * hsin(s2 * xf) + 0.3f * px;
        e.y = (xf >= lo && xf < hi) ? 1.0f : 0.0f;
        e.z = -0.6f * px;
        e.w = __expf(d * d * nk);
        xt4[t] = e;
        xr[t] = __fmul_rn(ca, xf - 16.0f);
    } else if (t < 64) {
        int   y  = t - 32;
        float yf = (float)y;
        float qy = fdivq(yf, cb, rcb);
        float py = qy - 2.0f * floorf(qy * 0.5f);
        float d  = yf - bxy;
        float4 e;
        // bias, warp, 0.3py and the constant -0.5*k13 (noise_rand) all folded
        e.x = 0.5f * hsin(s3 * yf) + 0.5f * hsin(0.015625f * yf + s5o)
              + 0.3f * py + w6 - 0.5f * k13;
        e.y = (yf >= lo && yf < hi) ? 0.5f : 0.0f;
        e.z = py;
        e.w = __expf(d * d * nk);
        yt4[y + (y >> 3)] = e;
    } else if (t < 127) {
        int s = t - 64;
        stab[s] = 0.5f * hsin(s4 * (float)s);
    }
    __syncthreads();

    // per-thread (y-fixed) hoisted state
    int   y   = t & 31;
    int   x0  = t >> 5;                   // x = x0 + 8j
    float4 Y  = yt4[y + (y >> 3)];        // conflict-free padded read
    float yf  = (float)y;
    float sy  = __fmul_rn(sa, yf - 16.0f);   // rotated-line y term (un-fused)

    size_t base = (size_t)b * NPIX + (size_t)t;
    const float* nrp = nrand + base;
    const float* nup = nunif + base;
    const float* rp  = g_r + t;
    const float* tp  = g_th + t;

    const v2f Yx2 = {Y.x, Y.x}, Yy2 = {Y.y, Y.y}, Yz2 = {Y.z, Y.z},
              Yw2 = {Y.w, Y.w};
    const v2f a02 = {a0, a0}, sy2 = {sy, sy}, w112 = {w11, w11},
              k122 = {k12, k12}, k132 = {k13, k13}, h2 = {0.5f, 0.5f},
              z2 = {0.0f, 0.0f}, o2 = {1.0f, 1.0f};

    v2f img2[2];
    v2f mn2 = {1e30f, 1e30f}, mx2 = {-1e30f, -1e30f};

#pragma unroll
    for (int jp = 0; jp < 2; ++jp) {
        int xA = x0 + 16 * jp;            // pixel pair: x = xA, xA+8
        int oA = 512 * jp, oB = oA + 256;

        v2f r2  = { rp[oA],  rp[oB]  };
        v2f th2 = { tp[oA],  tp[oB]  };
        v2f nr2 = { nrp[oA], nrp[oB] };
        v2f nu2 = { nup[oA], nup[oB] };

        float4 XA = xt4[xA], XB = xt4[xA + 8];
        v2f Xx = {XA.x, XB.x}, Xy = {XA.y, XB.y}, Xz = {XA.z, XB.z},
            Xw = {XA.w, XB.w};
        v2f Rx = {xr[xA], xr[xA + 8]};
        v2f St = {stab[xA + y], stab[xA + 8 + y]};

        // layer 0: clipped radial cone (pk sub/max/min, IEEE-RN per comp)
        v2f v = __builtin_elementwise_min(
                    __builtin_elementwise_max(a02 - r2, z2), o2);
        // separable sums (x-part pair + y-part splat)
        v += Xx + Yx2;
        // layer 1: centered square (exact 0/1 x 0/0.5 masks)
        v = __builtin_elementwise_fma(Xy, Yy2, v);
        // layer 4: diagonal sinusoid
        v += St;
        // checker cross term: -0.6*px*py (exact on {0,1})
        v = __builtin_elementwise_fma(Xz, Yz2, v);
        // layer 7: gaussian blob, exp split (<=4e-7 abs err)
        v = __builtin_elementwise_fma(Xw, Yw2, v);
        // layer 8: ring — scalar bit-exact compares, packed mask add
        float dA = __fsub_rn(r2.x, t8), dB = __fsub_rn(r2.y, t8);
        v2f ring = { (__fmul_rn(dA, dA) < 10.0f) ? 1.0f : 0.0f,
                     (__fmul_rn(dB, dB) < 10.0f) ? 1.0f : 0.0f };
        v += ring;
        // layer 10: rotated line — pk_add(Rx, sy) == ref's mul,mul,add chain
        v2f rot = Rx + sy2;
        v2f line = { (fabsf(rot.x) < 3.0f) ? 0.6f : 0.0f,
                     (fabsf(rot.y) < 3.0f) ? 0.6f : 0.0f };
        v += line;
        // layer 11: angular sinusoid (scalar v_fract+v_sin, packed fma)
        v2f ang = th2 * w112;
        v2f sn = { __builtin_amdgcn_sinf(__builtin_amdgcn_fractf(ang.x)),
                   __builtin_amdgcn_sinf(__builtin_amdgcn_fractf(ang.y)) };
        v = __builtin_elementwise_fma(sn, h2, v);
        // layers 12-13: noise (-0.5*k13 constant folded into Yx)
        v = __builtin_elementwise_fma(nr2, k122, v);
        v = __builtin_elementwise_fma(nu2, k132, v);

        img2[jp] = v;
        mn2 = __builtin_elementwise_min(mn2, v);
        mx2 = __builtin_elementwise_max(mx2, v);
    }

    float mn = fminf(mn2.x, mn2.y);
    float mx = fmaxf(mx2.x, mx2.y);

    // wave (64-lane) butterfly reduce; contrast+inversion folded below
#pragma unroll
    for (int off = 32; off > 0; off >>= 1) {
        mn = fminf(mn, __shfl_xor(mn, off));
        mx = fmaxf(mx, __shfl_xor(mx, off));
    }
    __shared__ float smn[4], smx[4];
    int wid = t >> 6;
    if ((t & 63) == 0) { smn[wid] = mn; smx[wid] = mx; }
    __syncthreads();
    mn = fminf(fminf(smn[0], smn[1]), fminf(smn[2], smn[3]));
    mx = fmaxf(fmaxf(smx[0], smx[1]), fmaxf(smx[2], smx[3]));

    // contrast (v-0.5)*con+0.5, optional inversion, min-max normalize:
    // affine => one (v - base)*scale; flips tracked by sign of con and w15.
    float ac    = fabsf(con);
    float denom = fmaf(ac, mx - mn, 1e-8f);
    float s     = ac / denom;
    bool  eff   = (w15 > 0.0f) != (con < 0.0f);
    float bse   = eff ? mx : mn;
    float sgn   = eff ? -s : s;
    v2f bse2 = {bse, bse}, sgn2 = {sgn, sgn};

    float* op = out + base;
#pragma unroll
    for (int jp = 0; jp < 2; ++jp) {
        v2f o = (img2[jp] - bse2) * sgn2;
        op[512 * jp]       = o.x;
        op[512 * jp + 256] = o.y;
    }
}

extern "C" void kernel_launch(void* const* d_in, const int* in_sizes, int n_in,
                              void* d_out, int out_size, void* d_ws, size_t ws_size,
                              hipStream_t stream) {
    const float* W  = (const float*)d_in[0];
    const float* nr = (const float*)d_in[1];
    const float* nu = (const float*)d_in[2];
    float* out = (float*)d_out;

    init_params_kernel<<<NB / 256, 256, 0, stream>>>(W);
    decode_kernel<<<NB, 256, 0, stream>>>(nr, nu, out);
}

// Round 6
// 152.623 us; speedup vs baseline: 1.0029x; 1.0029x over previous
//
#include <hip/hip_runtime.h>
#include <math.h>

#define NB 65536
#define IMGD 32
#define NPIX 1024
#define PSTRIDE 20

typedef float v2f __attribute__((ext_vector_type(2)));

// Packed FP32 (VOP3P, full-rate on CDNA3/4). Compiler never forms these from
// scalar f32 -> emit directly. 64-bit "v" operands = aligned VGPR pairs.
#define PK_FMA(d, a, b, c) \
    asm("v_pk_fma_f32 %0, %1, %2, %3" : "=v"(d) : "v"(a), "v"(b), "v"(c))
#define PK_FMA_CLAMP(d, a, b, c) \
    asm("v_pk_fma_f32 %0, %1, %2, %3 clamp" : "=v"(d) : "v"(a), "v"(b), "v"(c))
#define PK_FMA_ACC(acc, a, b) \
    asm("v_pk_fma_f32 %0, %1, %2, %0" : "+v"(acc) : "v"(a), "v"(b))
#define PK_ADD(d, a, b) \
    asm("v_pk_add_f32 %0, %1, %2" : "=v"(d) : "v"(a), "v"(b))
#define PK_ADD_ACC(acc, a) \
    asm("v_pk_add_f32 %0, %0, %1" : "+v"(acc) : "v"(a))
#define PK_MUL(d, a, b) \
    asm("v_pk_mul_f32 %0, %1, %2" : "=v"(d) : "v"(a), "v"(b))

// Constant tables (same for every image) and per-image derived params.
__device__ __align__(16) float g_r[NPIX];
__device__ __align__(16) float g_th[NPIX];   // theta * 5/(2*pi)
__device__ __align__(16) float g_par[(size_t)NB * PSTRIDE];

__global__ void init_params_kernel(const float* __restrict__ W) {
    int b = blockIdx.x * blockDim.x + threadIdx.x;

    // block 0 additionally fills the constant pixel tables (4 px/thread)
    if (blockIdx.x == 0) {
        int t = threadIdx.x;
        for (int k = 0; k < 4; ++k) {
            int p = t * 4 + k;
            int x = p >> 5, y = p & 31;
            float dx = (float)(x - 16), dy = (float)(y - 16);
            // exact integer squares; sqrtf correctly rounded -> bitwise match
            g_r[p] = sqrtf(dx * dx + dy * dy);
            // theta = atan2(yy-CY, xx-CX); fold 5/(2*pi) for revolution sin
            g_th[p] = atan2f(dy, dx) * 0.79577471545947668f;
        }
    }
    if (b >= NB) return;
    const float* w = W + (size_t)b * 16;
    float* P = g_par + (size_t)b * PSTRIDE;

    float w0 = w[0], w1 = w[1], w2 = w[2], w3 = w[3], w4 = w[4], w5 = w[5],
          w6 = w[6], w7 = w[7], w8 = w[8], w9 = w[9], w10 = w[10], w11 = w[11],
          w12 = w[12], w13 = w[13], w14 = w[14], w15 = w[15];

    P[0] = w0 * 5.0f;                                   // a0
    // layer 1: half = floor(clip(|w1|*8, 2, 12)); |w1|*8 exact (pow2 mul)
    float half = floorf(fminf(fmaxf(fabsf(w1) * 8.0f, 2.0f), 12.0f));
    P[1] = 16.0f - half;                                // lo (exact)
    P[2] = 16.0f + half;                                // hi (exact)
    P[3] = w2 * 0.15625f;                               // s2 (10/64 rev)
    P[4] = w3 * 0.15625f;                               // s3
    P[5] = w4 * 0.0390625f;                             // s4 (5/128 rev)
    P[6] = w5 * 0.15625f;                               // s5o
    P[7] = w6;                                          // bias
    // layer 7 blob center: trunc(16 + w7*5), mul/add un-fused to match ref
    float t7 = __fadd_rn(16.0f, __fmul_rn(w7, 5.0f));
    P[8] = truncf(t7);                                  // bxy
    float sg = 4.0f + fabsf(w7) * 4.0f;
    P[9] = -1.0f / (2.0f * sg * sg);                    // nk
    P[10] = w8 * 10.0f;                                 // t8 (single mul)
    // layer 9: cb = floor(clip(|w9|*8 + 2, 2, 16)); exact chain
    float cb = floorf(fminf(fmaxf(__fadd_rn(fabsf(w9) * 8.0f, 2.0f), 2.0f), 16.0f));
    P[11] = cb;
    P[12] = 1.0f / cb;
    // layer 10: angle = w10 * f32(pi) rounded once; cos/sin of that exact f32
    // in DOUBLE then rounded -> correctly-rounded f32 (matches numpy; OCML's
    // 1-2ulp f32 trig flipped |rot|<3 on border px -> round-1's 0.10 absmax).
    float ang = __fmul_rn(w10, 3.14159265358979323846f);
    P[13] = (float)cos((double)ang);                    // ca
    P[14] = (float)sin((double)ang);                    // sa
    P[15] = w11;
    P[16] = w12 * 0.1f;                                 // k12
    P[17] = w13 * 0.05f;                                // k13
    P[18] = 1.0f + w14;                                 // con
    P[19] = w15;
}

// sin(2*pi*rev): v_fract_f32 + v_sin_f32
__device__ __forceinline__ float hsin(float rev) {
    return __builtin_amdgcn_sinf(__builtin_amdgcn_fractf(rev));
}

// Exact floor(x/cb) for integer-valued x in [0,32), cb in [2,16].
__device__ __forceinline__ float fdivq(float xf, float cb, float rcb) {
    float q = floorf(xf * rcb);
    q += ((q + 1.0f) * cb <= xf) ? 1.0f : 0.0f;
    q -= ((q * cb) > xf) ? 1.0f : 0.0f;
    return q;
}

// One block = one image. Thread t: x = t>>3 FIXED, y = 4(t&7)..+3.
// Global IO is dwordx4; y-tables are SoA (aligned b64 pair reads, 8-lane
// broadcast -> conflict-free); x-work hoisted per thread; additive chain in
// packed-f32 inline asm. Discrete layers scalar on RN-exact pk inputs.
__global__ __launch_bounds__(256) void decode_kernel(
        const float* __restrict__ nrand,   // noise_randn
        const float* __restrict__ nunif,   // noise_rand
        float* __restrict__ out) {
    int b = blockIdx.x;
    int t = threadIdx.x;

    const float4* Pq = (const float4*)(g_par + (size_t)b * PSTRIDE);
    float4 q0 = Pq[0], q1 = Pq[1], q2 = Pq[2], q3 = Pq[3], q4 = Pq[4];
    float a0 = q0.x, lo = q0.y, hi = q0.z, s2 = q0.w;
    float s3 = q1.x, s4 = q1.y, s5o = q1.z, w6 = q1.w;
    float bxy = q2.x, nk = q2.y, t8 = q2.z, cb = q2.w;
    float rcb = q3.x, ca = q3.y, sa = q3.z, w11 = q3.w;
    float k12 = q4.x, k13 = q4.y, con = q4.z, w15 = q4.w;

    __shared__ float4 xt4[32];     // {xsum=0.5sin2+0.3px, xm(0/1), -0.6px, gx}
    __shared__ float  rx[32];      // ca*(x-16) un-fused
    __shared__ float  ysum[32];    // 0.5sin3+0.5warp+0.3py+w6-0.5k13
    __shared__ float  ym05[32];    // square y mask (0/0.5)
    __shared__ float  pyt[32];     // checker y parity (0/1)
    __shared__ float  gyt[32];     // exp(nk*dy^2)
    __shared__ float  syt[32];     // sa*(y-16) un-fused
    __shared__ float  stab[63];    // 0.5*sin4(x+y)

    if (t < 32) {
        float xf = (float)t;
        float qx = fdivq(xf, cb, rcb);
        float px = qx - 2.0f * floorf(qx * 0.5f);       // parity 0/1, exact
        float d  = xf - bxy;
        float4 e;
        e.x = 0.5f * hsin(s2 * xf) + 0.3f * px;
        e.y = (xf >= lo && xf < hi) ? 1.0f : 0.0f;
        e.z = -0.6f * px;
        e.w = __expf(d * d * nk);
        xt4[t] = e;
        rx[t] = __fmul_rn(ca, xf - 16.0f);
    } else if (t < 64) {
        int   y  = t - 32;
        float yf = (float)y;
        float qy = fdivq(yf, cb, rcb);
        float py = qy - 2.0f * floorf(qy * 0.5f);
        float d  = yf - bxy;
        ysum[y] = 0.5f * hsin(s3 * yf) + 0.5f * hsin(0.015625f * yf + s5o)
                  + 0.3f * py + w6 - 0.5f * k13;
        ym05[y] = (yf >= lo && yf < hi) ? 0.5f : 0.0f;
        pyt[y]  = py;
        gyt[y]  = __expf(d * d * nk);
        syt[y]  = __fmul_rn(sa, yf - 16.0f);
    } else if (t < 127) {
        int s = t - 64;
        stab[s] = 0.5f * hsin(s4 * (float)s);
    }
    __syncthreads();

    int x  = t >> 3;
    int y0 = (t & 7) * 4;

    float4 X   = xt4[x];
    float  rxv = rx[x];

    // y-pair tables: aligned ds_read_b64, same-addr broadcast across lanes
    v2f ysA = *(const v2f*)&ysum[y0], ysB = *(const v2f*)&ysum[y0 + 2];
    v2f ymA = *(const v2f*)&ym05[y0], ymB = *(const v2f*)&ym05[y0 + 2];
    v2f pyA = *(const v2f*)&pyt[y0],  pyB = *(const v2f*)&pyt[y0 + 2];
    v2f gyA = *(const v2f*)&gyt[y0],  gyB = *(const v2f*)&gyt[y0 + 2];
    v2f syA = *(const v2f*)&syt[y0],  syB = *(const v2f*)&syt[y0 + 2];
    int s0 = x + y0;
    v2f stA = {stab[s0], stab[s0 + 1]}, stB = {stab[s0 + 2], stab[s0 + 3]};

    size_t q = (size_t)b * 256 + (size_t)t;    // float4 index
    float4 R  = ((const float4*)g_r)[t];
    float4 TH = ((const float4*)g_th)[t];
    float4 NR = ((const float4*)nrand)[q];
    float4 NU = ((const float4*)nunif)[q];

    const v2f m1   = {-1.0f, -1.0f};
    const v2f a02  = {a0, a0};
    const v2f xs2  = {X.x, X.x};
    const v2f xm2  = {X.y, X.y};
    const v2f px2  = {X.z, X.z};
    const v2f gx2  = {X.w, X.w};
    const v2f rx2  = {rxv, rxv};
    const v2f nt82 = {-t8, -t8};
    const v2f w112 = {w11, w11};
    const v2f h2   = {0.5f, 0.5f};
    const v2f k122 = {k12, k12};
    const v2f k132 = {k13, k13};

    v2f i01, i23;
    float mn, mx;

#pragma unroll
    for (int k = 0; k < 2; ++k) {
        v2f r2  = k ? (v2f){R.z, R.w}   : (v2f){R.x, R.y};
        v2f th2 = k ? (v2f){TH.z, TH.w} : (v2f){TH.x, TH.y};
        v2f nr2 = k ? (v2f){NR.z, NR.w} : (v2f){NR.x, NR.y};
        v2f nu2 = k ? (v2f){NU.z, NU.w} : (v2f){NU.x, NU.y};
        v2f ys = k ? ysB : ysA, ym = k ? ymB : ymA, py = k ? pyB : pyA;
        v2f gy = k ? gyB : gyA, sy = k ? syB : syA, st = k ? stB : stA;

        v2f v;
        PK_FMA_CLAMP(v, r2, m1, a02);   // layer 0: clip(a0 - r, 0, 1)
        PK_ADD_ACC(v, ys);              // sin3+warp+0.3py+bias-0.5k13
        PK_ADD_ACC(v, xs2);             // sin2+0.3px
        PK_ADD_ACC(v, st);              // diagonal sinusoid
        PK_FMA_ACC(v, xm2, ym);         // layer 1: square (exact masks)
        PK_FMA_ACC(v, px2, py);         // checker cross: -0.6*px*py (exact)
        PK_FMA_ACC(v, gx2, gy);         // gaussian split (<=4e-7)
        v2f dr, dr2, rot, ang;
        PK_ADD(dr, r2, nt82);           // RN(r - t8)  == __fsub_rn
        PK_MUL(dr2, dr, dr);            // RN(dr*dr)   == __fmul_rn
        PK_ADD(rot, sy, rx2);           // RN(ca(x-16) + sa(y-16))
        PK_MUL(ang, th2, w112);
        v2f sn = {hsin(ang.x), hsin(ang.y)};
        PK_FMA_ACC(v, sn, h2);          // angular sinusoid
        PK_FMA_ACC(v, nr2, k122);       // noise_randn
        PK_FMA_ACC(v, nu2, k132);       // noise_rand (-0.5k13 in ysum)

        // discrete mask adds: scalar, bit-exact compare inputs from pk RN ops
        float vx = v.x + ((dr2.x < 10.0f) ? 1.0f : 0.0f);
        float vy = v.y + ((dr2.y < 10.0f) ? 1.0f : 0.0f);
        vx += (fabsf(rot.x) < 3.0f) ? 0.6f : 0.0f;
        vy += (fabsf(rot.y) < 3.0f) ? 0.6f : 0.0f;

        v2f r_ = {vx, vy};
        if (k == 0) { i01 = r_; mn = fminf(vx, vy); mx = fmaxf(vx, vy); }
        else        { i23 = r_; mn = fminf(mn, fminf(vx, vy));
                                mx = fmaxf(mx, fmaxf(vx, vy)); }
    }

    // wave (64-lane) butterfly reduce; contrast+inversion folded below
#pragma unroll
    for (int off = 32; off > 0; off >>= 1) {
        mn = fminf(mn, __shfl_xor(mn, off));
        mx = fmaxf(mx, __shfl_xor(mx, off));
    }
    __shared__ float smn[4], smx[4];
    int wid = t >> 6;
    if ((t & 63) == 0) { smn[wid] = mn; smx[wid] = mx; }
    __syncthreads();
    mn = fminf(fminf(smn[0], smn[1]), fminf(smn[2], smn[3]));
    mx = fmaxf(fmaxf(smx[0], smx[1]), fmaxf(smx[2], smx[3]));

    // contrast (v-0.5)*con+0.5, optional inversion, min-max normalize:
    // affine => o = v*sgn + c0; flips tracked by signs of con and w15.
    float ac    = fabsf(con);
    float denom = fmaf(ac, mx - mn, 1e-8f);
    float s     = ac / denom;
    bool  eff   = (w15 > 0.0f) != (con < 0.0f);
    float bse   = eff ? mx : mn;
    float sgn   = eff ? -s : s;
    v2f c12 = {sgn, sgn};
    v2f c02 = {-bse * sgn, -bse * sgn};

    v2f o01, o23;
    PK_FMA(o01, i01, c12, c02);
    PK_FMA(o23, i23, c12, c02);
    float4 O = {o01.x, o01.y, o23.x, o23.y};
    ((float4*)out)[q] = O;
}

extern "C" void kernel_launch(void* const* d_in, const int* in_sizes, int n_in,
                              void* d_out, int out_size, void* d_ws, size_t ws_size,
                              hipStream_t stream) {
    const float* W  = (const float*)d_in[0];
    const float* nr = (const float*)d_in[1];
    const float* nu = (const float*)d_in[2];
    float* out = (float*)d_out;

    init_params_kernel<<<NB / 256, 256, 0, stream>>>(W);
    decode_kernel<<<NB, 256, 0, stream>>>(nr, nu, out);
}

// Round 11
// 145.858 us; speedup vs baseline: 1.0495x; 1.0464x over previous
//
#include <hip/hip_runtime.h>
#include <math.h>

#define NB 65536
#define IMGD 32
#define NPIX 1024
#define PSTRIDE 20

typedef float v2f __attribute__((ext_vector_type(2)));

// Packed FP32 (VOP3P, full-rate on CDNA3/4). Compiler never forms these from
// scalar f32 -> emit directly. 64-bit "v" operands = aligned VGPR pairs.
#define PK_FMA(d, a, b, c) \
    asm("v_pk_fma_f32 %0, %1, %2, %3" : "=v"(d) : "v"(a), "v"(b), "v"(c))
#define PK_FMA_CLAMP(d, a, b, c) \
    asm("v_pk_fma_f32 %0, %1, %2, %3 clamp" : "=v"(d) : "v"(a), "v"(b), "v"(c))
#define PK_FMA_ACC(acc, a, b) \
    asm("v_pk_fma_f32 %0, %1, %2, %0" : "+v"(acc) : "v"(a), "v"(b))
#define PK_ADD(d, a, b) \
    asm("v_pk_add_f32 %0, %1, %2" : "=v"(d) : "v"(a), "v"(b))
#define PK_ADD_ACC(acc, a) \
    asm("v_pk_add_f32 %0, %0, %1" : "+v"(acc) : "v"(a))
#define PK_MUL(d, a, b) \
    asm("v_pk_mul_f32 %0, %1, %2" : "=v"(d) : "v"(a), "v"(b))

// Constant tables (same for every image) and per-image derived params.
__device__ __align__(16) float g_r[NPIX];
__device__ __align__(16) float g_th[NPIX];   // theta * 5/(2*pi)
__device__ __align__(16) float g_par[(size_t)NB * PSTRIDE];

__global__ void init_params_kernel(const float* __restrict__ W) {
    int b = blockIdx.x * blockDim.x + threadIdx.x;

    // block 0 additionally fills the constant pixel tables (4 px/thread)
    if (blockIdx.x == 0) {
        int t = threadIdx.x;
        for (int k = 0; k < 4; ++k) {
            int p = t * 4 + k;
            int x = p >> 5, y = p & 31;
            float dx = (float)(x - 16), dy = (float)(y - 16);
            // exact integer squares; sqrtf correctly rounded -> bitwise match
            g_r[p] = sqrtf(dx * dx + dy * dy);
            // theta = atan2(yy-CY, xx-CX); fold 5/(2*pi) for revolution sin
            g_th[p] = atan2f(dy, dx) * 0.79577471545947668f;
        }
    }
    if (b >= NB) return;
    const float* w = W + (size_t)b * 16;
    float* P = g_par + (size_t)b * PSTRIDE;

    float w0 = w[0], w1 = w[1], w2 = w[2], w3 = w[3], w4 = w[4], w5 = w[5],
          w6 = w[6], w7 = w[7], w8 = w[8], w9 = w[9], w10 = w[10], w11 = w[11],
          w12 = w[12], w13 = w[13], w14 = w[14], w15 = w[15];

    P[0] = w0 * 5.0f;                                   // a0
    // layer 1: half = floor(clip(|w1|*8, 2, 12)); |w1|*8 exact (pow2 mul)
    float half = floorf(fminf(fmaxf(fabsf(w1) * 8.0f, 2.0f), 12.0f));
    P[1] = 16.0f - half;                                // lo (exact)
    P[2] = 16.0f + half;                                // hi (exact)
    P[3] = w2 * 0.15625f;                               // s2 (10/64 rev)
    P[4] = w3 * 0.15625f;                               // s3
    P[5] = w4 * 0.0390625f;                             // s4 (5/128 rev)
    P[6] = w5 * 0.15625f;                               // s5o
    P[7] = w6;                                          // bias
    // layer 7 blob center: trunc(16 + w7*5), mul/add un-fused to match ref
    float t7 = __fadd_rn(16.0f, __fmul_rn(w7, 5.0f));
    P[8] = truncf(t7);                                  // bxy
    float sg = 4.0f + fabsf(w7) * 4.0f;
    P[9] = -1.0f / (2.0f * sg * sg);                    // nk
    P[10] = w8 * 10.0f;                                 // t8 (single mul)
    // layer 9: cb = floor(clip(|w9|*8 + 2, 2, 16)); exact chain
    float cb = floorf(fminf(fmaxf(__fadd_rn(fabsf(w9) * 8.0f, 2.0f), 2.0f), 16.0f));
    P[11] = cb;
    P[12] = 1.0f / cb;
    // layer 10: angle = w10 * f32(pi) rounded once; cos/sin of that exact f32
    // in DOUBLE then rounded -> correctly-rounded f32 (matches numpy; OCML's
    // 1-2ulp f32 trig flipped |rot|<3 on border px -> round-1's 0.10 absmax).
    float ang = __fmul_rn(w10, 3.14159265358979323846f);
    P[13] = (float)cos((double)ang);                    // ca
    P[14] = (float)sin((double)ang);                    // sa
    P[15] = w11;
    P[16] = w12 * 0.1f;                                 // k12
    P[17] = w13 * 0.05f;                                // k13
    P[18] = 1.0f + w14;                                 // con
    P[19] = w15;
}

// sin(2*pi*rev): v_fract_f32 + v_sin_f32
__device__ __forceinline__ float hsin(float rev) {
    return __builtin_amdgcn_sinf(__builtin_amdgcn_fractf(rev));
}

// Exact floor(x/cb) for integer-valued x in [0,32), cb in [2,16].
__device__ __forceinline__ float fdivq(float xf, float cb, float rcb) {
    float q = floorf(xf * rcb);
    q += ((q + 1.0f) * cb <= xf) ? 1.0f : 0.0f;
    q -= ((q * cb) > xf) ? 1.0f : 0.0f;
    return q;
}

// Wave64 min/max reduction on the VALU pipe via DPP (row_shr 1/2/4/8 +
// row_bcast:15/31, then readlane 63). Replaces 12 dependent ds_bpermute
// (__shfl_xor) levels: zero LDS-pipe traffic, compiler-managed hazards.
// bound_ctrl=false + old=v -> invalid-source lanes fold v (idempotent).
// NOTE: dpp_ctrl must be an integer-constant-expression -> template param.
template <int CTRL>
__device__ __forceinline__ float dpp_step_min(float v) {
    int i = __float_as_int(v);
    int s = __builtin_amdgcn_update_dpp(i, i, CTRL, 0xf, 0xf, false);
    return fminf(v, __int_as_float(s));
}
template <int CTRL>
__device__ __forceinline__ float dpp_step_max(float v) {
    int i = __float_as_int(v);
    int s = __builtin_amdgcn_update_dpp(i, i, CTRL, 0xf, 0xf, false);
    return fmaxf(v, __int_as_float(s));
}

// One block = one image. Thread t: x = t>>3 FIXED, y = 4(t&7)..+3.
// (Exact round-5 structure — the only change vs R5 is the DPP reduction.)
__global__ __launch_bounds__(256) void decode_kernel(
        const float* __restrict__ nrand,   // noise_randn
        const float* __restrict__ nunif,   // noise_rand
        float* __restrict__ out) {
    int b = blockIdx.x;
    int t = threadIdx.x;

    const float4* Pq = (const float4*)(g_par + (size_t)b * PSTRIDE);
    float4 q0 = Pq[0], q1 = Pq[1], q2 = Pq[2], q3 = Pq[3], q4 = Pq[4];
    float a0 = q0.x, lo = q0.y, hi = q0.z, s2 = q0.w;
    float s3 = q1.x, s4 = q1.y, s5o = q1.z, w6 = q1.w;
    float bxy = q2.x, nk = q2.y, t8 = q2.z, cb = q2.w;
    float rcb = q3.x, ca = q3.y, sa = q3.z, w11 = q3.w;
    float k12 = q4.x, k13 = q4.y, con = q4.z, w15 = q4.w;

    __shared__ float4 xt4[32];     // {xsum=0.5sin2+0.3px, xm(0/1), -0.6px, gx}
    __shared__ float  rx[32];      // ca*(x-16) un-fused
    __shared__ float  ysum[32];    // 0.5sin3+0.5warp+0.3py+w6-0.5k13
    __shared__ float  ym05[32];    // square y mask (0/0.5)
    __shared__ float  pyt[32];     // checker y parity (0/1)
    __shared__ float  gyt[32];     // exp(nk*dy^2)
    __shared__ float  syt[32];     // sa*(y-16) un-fused
    __shared__ float  stab[63];    // 0.5*sin4(x+y)

    if (t < 32) {
        float xf = (float)t;
        float qx = fdivq(xf, cb, rcb);
        float px = qx - 2.0f * floorf(qx * 0.5f);       // parity 0/1, exact
        float d  = xf - bxy;
        float4 e;
        e.x = 0.5f * hsin(s2 * xf) + 0.3f * px;
        e.y = (xf >= lo && xf < hi) ? 1.0f : 0.0f;
        e.z = -0.6f * px;
        e.w = __expf(d * d * nk);
        xt4[t] = e;
        rx[t] = __fmul_rn(ca, xf - 16.0f);
    } else if (t < 64) {
        int   y  = t - 32;
        float yf = (float)y;
        float qy = fdivq(yf, cb, rcb);
        float py = qy - 2.0f * floorf(qy * 0.5f);
        float d  = yf - bxy;
        ysum[y] = 0.5f * hsin(s3 * yf) + 0.5f * hsin(0.015625f * yf + s5o)
                  + 0.3f * py + w6 - 0.5f * k13;
        ym05[y] = (yf >= lo && yf < hi) ? 0.5f : 0.0f;
        pyt[y]  = py;
        gyt[y]  = __expf(d * d * nk);
        syt[y]  = __fmul_rn(sa, yf - 16.0f);
    } else if (t < 127) {
        int s = t - 64;
        stab[s] = 0.5f * hsin(s4 * (float)s);
    }
    __syncthreads();

    int x  = t >> 3;
    int y0 = (t & 7) * 4;

    float4 X   = xt4[x];
    float  rxv = rx[x];

    // y-pair tables: aligned ds_read_b64, same-addr broadcast across lanes
    v2f ysA = *(const v2f*)&ysum[y0], ysB = *(const v2f*)&ysum[y0 + 2];
    v2f ymA = *(const v2f*)&ym05[y0], ymB = *(const v2f*)&ym05[y0 + 2];
    v2f pyA = *(const v2f*)&pyt[y0],  pyB = *(const v2f*)&pyt[y0 + 2];
    v2f gyA = *(const v2f*)&gyt[y0],  gyB = *(const v2f*)&gyt[y0 + 2];
    v2f syA = *(const v2f*)&syt[y0],  syB = *(const v2f*)&syt[y0 + 2];
    int s0 = x + y0;
    v2f stA = {stab[s0], stab[s0 + 1]}, stB = {stab[s0 + 2], stab[s0 + 3]};

    size_t q = (size_t)b * 256 + (size_t)t;    // float4 index
    float4 R  = ((const float4*)g_r)[t];
    float4 TH = ((const float4*)g_th)[t];
    float4 NR = ((const float4*)nrand)[q];
    float4 NU = ((const float4*)nunif)[q];

    const v2f m1   = {-1.0f, -1.0f};
    const v2f a02  = {a0, a0};
    const v2f xs2  = {X.x, X.x};
    const v2f xm2  = {X.y, X.y};
    const v2f px2  = {X.z, X.z};
    const v2f gx2  = {X.w, X.w};
    const v2f rx2  = {rxv, rxv};
    const v2f nt82 = {-t8, -t8};
    const v2f w112 = {w11, w11};
    const v2f h2   = {0.5f, 0.5f};
    const v2f k122 = {k12, k12};
    const v2f k132 = {k13, k13};

    v2f i01, i23;
    float mn, mx;

#pragma unroll
    for (int k = 0; k < 2; ++k) {
        v2f r2  = k ? (v2f){R.z, R.w}   : (v2f){R.x, R.y};
        v2f th2 = k ? (v2f){TH.z, TH.w} : (v2f){TH.x, TH.y};
        v2f nr2 = k ? (v2f){NR.z, NR.w} : (v2f){NR.x, NR.y};
        v2f nu2 = k ? (v2f){NU.z, NU.w} : (v2f){NU.x, NU.y};
        v2f ys = k ? ysB : ysA, ym = k ? ymB : ymA, py = k ? pyB : pyA;
        v2f gy = k ? gyB : gyA, sy = k ? syB : syA, st = k ? stB : stA;

        v2f v;
        PK_FMA_CLAMP(v, r2, m1, a02);   // layer 0: clip(a0 - r, 0, 1)
        PK_ADD_ACC(v, ys);              // sin3+warp+0.3py+bias-0.5k13
        PK_ADD_ACC(v, xs2);             // sin2+0.3px
        PK_ADD_ACC(v, st);              // diagonal sinusoid
        PK_FMA_ACC(v, xm2, ym);         // layer 1: square (exact masks)
        PK_FMA_ACC(v, px2, py);         // checker cross: -0.6*px*py (exact)
        PK_FMA_ACC(v, gx2, gy);         // gaussian split (<=4e-7)
        v2f dr, dr2, rot, ang;
        PK_ADD(dr, r2, nt82);           // RN(r - t8)  == __fsub_rn
        PK_MUL(dr2, dr, dr);            // RN(dr*dr)   == __fmul_rn
        PK_ADD(rot, sy, rx2);           // RN(ca(x-16) + sa(y-16))
        PK_MUL(ang, th2, w112);
        v2f sn = {hsin(ang.x), hsin(ang.y)};
        PK_FMA_ACC(v, sn, h2);          // angular sinusoid
        PK_FMA_ACC(v, nr2, k122);       // noise_randn
        PK_FMA_ACC(v, nu2, k132);       // noise_rand (-0.5k13 in ysum)

        // discrete mask adds: scalar, bit-exact compare inputs from pk RN ops
        float vx = v.x + ((dr2.x < 10.0f) ? 1.0f : 0.0f);
        float vy = v.y + ((dr2.y < 10.0f) ? 1.0f : 0.0f);
        vx += (fabsf(rot.x) < 3.0f) ? 0.6f : 0.0f;
        vy += (fabsf(rot.y) < 3.0f) ? 0.6f : 0.0f;

        v2f r_ = {vx, vy};
        if (k == 0) { i01 = r_; mn = fminf(vx, vy); mx = fmaxf(vx, vy); }
        else        { i23 = r_; mn = fminf(mn, fminf(vx, vy));
                                mx = fmaxf(mx, fmaxf(vx, vy)); }
    }

    // wave64 reduce on VALU pipe (DPP), result broadcast via lane 63
    mn = dpp_step_min<0x111>(mn);   // row_shr:1
    mx = dpp_step_max<0x111>(mx);
    mn = dpp_step_min<0x112>(mn);   // row_shr:2
    mx = dpp_step_max<0x112>(mx);
    mn = dpp_step_min<0x114>(mn);   // row_shr:4
    mx = dpp_step_max<0x114>(mx);
    mn = dpp_step_min<0x118>(mn);   // row_shr:8
    mx = dpp_step_max<0x118>(mx);
    mn = dpp_step_min<0x142>(mn);   // row_bcast:15
    mx = dpp_step_max<0x142>(mx);
    mn = dpp_step_min<0x143>(mn);   // row_bcast:31
    mx = dpp_step_max<0x143>(mx);
    mn = __int_as_float(__builtin_amdgcn_readlane(__float_as_int(mn), 63));
    mx = __int_as_float(__builtin_amdgcn_readlane(__float_as_int(mx), 63));

    __shared__ float smn[4], smx[4];
    int wid = t >> 6;
    if ((t & 63) == 0) { smn[wid] = mn; smx[wid] = mx; }
    __syncthreads();
    mn = fminf(fminf(smn[0], smn[1]), fminf(smn[2], smn[3]));
    mx = fmaxf(fmaxf(smx[0], smx[1]), fmaxf(smx[2], smx[3]));

    // contrast (v-0.5)*con+0.5, optional inversion, min-max normalize:
    // affine => o = v*sgn + c0; flips tracked by signs of con and w15.
    float ac    = fabsf(con);
    float denom = fmaf(ac, mx - mn, 1e-8f);
    float s     = ac / denom;
    bool  eff   = (w15 > 0.0f) != (con < 0.0f);
    float bse   = eff ? mx : mn;
    float sgn   = eff ? -s : s;
    v2f c12 = {sgn, sgn};
    v2f c02 = {-bse * sgn, -bse * sgn};

    v2f o01, o23;
    PK_FMA(o01, i01, c12, c02);
    PK_FMA(o23, i23, c12, c02);
    float4 O = {o01.x, o01.y, o23.x, o23.y};
    ((float4*)out)[q] = O;
}

extern "C" void kernel_launch(void* const* d_in, const int* in_sizes, int n_in,
                              void* d_out, int out_size, void* d_ws, size_t ws_size,
                              hipStream_t stream) {
    const float* W  = (const float*)d_in[0];
    const float* nr = (const float*)d_in[1];
    const float* nu = (const float*)d_in[2];
    float* out = (float*)d_out;

    init_params_kernel<<<NB / 256, 256, 0, stream>>>(W);
    decode_kernel<<<NB, 256, 0, stream>>>(nr, nu, out);
}